// Round 3
// baseline (536.774 us; speedup 1.0000x reference)
//
#include <hip/hip_runtime.h>
#include <hip/hip_bf16.h>

#define B_  8
#define C_  64
#define H_  256
#define W_  256
#define HW_ (H_ * W_)
#define NP_ 25          // NUM_POINTS
#define NA_ 28          // N + 3
#define NCOLS_ 30       // NA_ + 2 RHS cols (one batch)

// Ticket layout: [0,2048) mean half-channels; [2048,2056) solve b; [2056,4104) sample (b,y)
#define TK_MEAN_END  2048
#define TK_SOLVE_END 2056
#define TK_TOTAL     4104

// flags (int32) in workspace
#define F_TICKET 0
#define F_MEAND  8    // [8..15]  per-batch mean-done count (target 256)
#define F_SOLVED 16   // [16..23] per-batch solve-done flag

typedef float f32x4 __attribute__((ext_vector_type(4)));

__global__ __launch_bounds__(256) void fused_kernel(const float* __restrict__ t,
                                                    const float* __restrict__ rgb,
                                                    const float* __restrict__ fc_w,
                                                    const float* __restrict__ fc_b,
                                                    const float* __restrict__ init_cp,
                                                    float* __restrict__ out,
                                                    float* __restrict__ cp_out,
                                                    int* __restrict__ flags,
                                                    float* __restrict__ feat_part,
                                                    double* __restrict__ Wm) {
    __shared__ int s_ticket;
    int tid = threadIdx.x;

    for (;;) {
        if (tid == 0)
            s_ticket = __hip_atomic_fetch_add(&flags[F_TICKET], 1,
                                              __ATOMIC_RELAXED, __HIP_MEMORY_SCOPE_AGENT);
        __syncthreads();
        int tk = s_ticket;
        if (tk >= TK_TOTAL) return;

        if (tk < TK_MEAN_END) {
            // ---------------- mean half-channel ----------------
            int b = tk >> 8;              // 8 batches x 256 tickets
            int c = (tk >> 1) & 127;      // channel in concat([t, rgb])
            int h = tk & 1;               // half
            bool is_rgb = (c >= C_);
            const float* base = (is_rgb ? rgb + ((size_t)(b * C_ + (c - C_))) * HW_
                                        : t   + ((size_t)(b * C_ + c)) * HW_)
                                + h * (HW_ / 2);
            const f32x4* s4 = (const f32x4*)base;
            float acc = 0.f;
            if (is_rgb) {
                #pragma unroll 4
                for (int k = 0; k < 32; ++k) {
                    f32x4 v = __builtin_nontemporal_load(s4 + tid + k * 256);
                    acc += (v.x + v.y) + (v.z + v.w);
                }
            } else {
                #pragma unroll 4
                for (int k = 0; k < 32; ++k) {
                    f32x4 v = s4[tid + k * 256];
                    acc += (v.x + v.y) + (v.z + v.w);
                }
            }
            #pragma unroll
            for (int off = 32; off > 0; off >>= 1) acc += __shfl_down(acc, off);
            __shared__ float red[4];
            if ((tid & 63) == 0) red[tid >> 6] = acc;
            __syncthreads();
            if (tid == 0) {
                float tot = (red[0] + red[1]) + (red[2] + red[3]);
                feat_part[b * 256 + c * 2 + h] = tot * (1.0f / 65536.0f);
                __threadfence();
                __hip_atomic_fetch_add(&flags[F_MEAND + b], 1,
                                       __ATOMIC_RELEASE, __HIP_MEMORY_SCOPE_AGENT);
            }
        } else if (tk < TK_SOLVE_END) {
            // ---------------- per-batch TPS solve ----------------
            int b = tk - TK_MEAN_END;
            if (tid == 0) {
                while (__hip_atomic_load(&flags[F_MEAND + b],
                                         __ATOMIC_ACQUIRE, __HIP_MEMORY_SCOPE_AGENT) < 256) {
                    __builtin_amdgcn_s_sleep(7);
                    __builtin_amdgcn_s_sleep(7);
                }
            }
            __syncthreads();

            __shared__ float  s_cp2[2 * NP_];
            __shared__ double Pd[2 * NP_];
            __shared__ double A[NA_][NCOLS_];
            __shared__ double fcol[NA_];
            __shared__ int    s_piv;
            __shared__ double s_pv;

            if (tid < 2 * NP_) {
                float accv = fc_b[tid];
                const float* fp = feat_part + b * 256;
                const float* w  = fc_w + tid * 128;
                #pragma unroll 8
                for (int c2 = 0; c2 < 128; ++c2)
                    accv += (fp[2 * c2] + fp[2 * c2 + 1]) * w[c2];
                float cpv = init_cp[tid] + accv;
                s_cp2[tid] = cpv;
                cp_out[b * 2 * NP_ + tid] = cpv;      // second tuple output
                Pd[tid] = (double)init_cp[tid];
            }
            __syncthreads();

            for (int i = tid; i < NA_ * NCOLS_; i += 256) {
                int r = i / NCOLS_, cc = i % NCOLS_;
                double v;
                if (cc < NA_) {
                    if (r < NP_ && cc < NP_) {
                        double dx = Pd[r * 2] - Pd[cc * 2];
                        double dy = Pd[r * 2 + 1] - Pd[cc * 2 + 1];
                        double d2 = dx * dx + dy * dy;
                        v = d2 * log(d2 + 1e-6);
                    } else if (r < NP_) {
                        v = (cc == NP_) ? 1.0 : ((cc == NP_ + 1) ? Pd[r * 2] : Pd[r * 2 + 1]);
                    } else if (cc < NP_) {
                        v = (r == NP_) ? 1.0 : ((r == NP_ + 1) ? Pd[cc * 2] : Pd[cc * 2 + 1]);
                    } else {
                        v = 0.0;
                    }
                } else {
                    v = (r < NP_) ? (double)s_cp2[r * 2 + (cc - NA_)] : 0.0;
                }
                A[r][cc] = v;
            }
            __syncthreads();

            for (int k = 0; k < NA_; ++k) {
                if (tid == 0) {
                    int piv = k; double best = fabs(A[k][k]);
                    for (int r = k + 1; r < NA_; ++r) {
                        double v = fabs(A[r][k]);
                        if (v > best) { best = v; piv = r; }
                    }
                    s_piv = piv;
                }
                __syncthreads();
                int piv = s_piv;
                if (piv != k && tid < NCOLS_) {
                    double tmp = A[k][tid]; A[k][tid] = A[piv][tid]; A[piv][tid] = tmp;
                }
                __syncthreads();
                if (tid == 0) s_pv = 1.0 / A[k][k];
                __syncthreads();
                if (tid < NCOLS_) A[k][tid] *= s_pv;
                __syncthreads();
                if (tid < NA_) fcol[tid] = A[tid][k];
                __syncthreads();
                for (int i = tid; i < NA_ * NCOLS_; i += 256) {
                    int r = i / NCOLS_, j = i % NCOLS_;
                    if (r != k) A[r][j] -= fcol[r] * A[k][j];
                }
                __syncthreads();
            }

            if (tid < NA_ * 2) {
                int n = tid >> 1, k2 = tid & 1;
                Wm[b * (NA_ * 2) + n * 2 + k2] = A[n][NA_ + k2];
            }
            __syncthreads();
            if (tid == 0) {
                __threadfence();
                __hip_atomic_store(&flags[F_SOLVED + b], 1,
                                   __ATOMIC_RELEASE, __HIP_MEMORY_SCOPE_AGENT);
            }
        } else {
            // ---------------- sample one (b, y) row ----------------
            int u  = tk - TK_SOLVE_END;
            int sb = u >> 8;
            int y  = u & 255;
            if (tid == 0) {
                while (!__hip_atomic_load(&flags[F_SOLVED + sb],
                                          __ATOMIC_ACQUIRE, __HIP_MEMORY_SCOPE_AGENT)) {
                    for (int j = 0; j < 8; ++j) __builtin_amdgcn_s_sleep(7);
                }
            }
            __syncthreads();

            __shared__ float sW[NA_][2];
            __shared__ float sP2[NP_][2];
            if (tid < 2 * NA_)
                ((float*)sW)[tid] = (float)Wm[sb * (NA_ * 2) + tid];
            else if (tid < 2 * NA_ + 2 * NP_)
                ((float*)sP2)[tid - 2 * NA_] = init_cp[tid - 2 * NA_];
            __syncthreads();

            int x = tid;
            float px = -1.0f + (2.0f / (float)(W_ - 1)) * (float)x;
            float py = -1.0f + (2.0f / (float)(H_ - 1)) * (float)y;

            float ax = sW[NP_][0] + px * sW[NP_ + 1][0] + py * sW[NP_ + 2][0];
            float ay = sW[NP_][1] + px * sW[NP_ + 1][1] + py * sW[NP_ + 2][1];
            #pragma unroll
            for (int n = 0; n < NP_; ++n) {
                float dx = px - sP2[n][0];
                float dy = py - sP2[n][1];
                float d2 = dx * dx + dy * dy;
                float ub = d2 * logf(d2 + 1e-6f);
                ax += ub * sW[n][0];
                ay += ub * sW[n][1];
            }

            float xf = fminf(fmaxf((ax + 1.0f) * 0.5f * (float)(W_ - 1), 0.0f), (float)(W_ - 1));
            float yf = fminf(fmaxf((ay + 1.0f) * 0.5f * (float)(H_ - 1), 0.0f), (float)(H_ - 1));
            float x0f = floorf(xf), y0f = floorf(yf);
            int x0 = (int)x0f, y0 = (int)y0f;
            int x1 = min(x0 + 1, W_ - 1);
            int y1 = min(y0 + 1, H_ - 1);
            float wx = xf - x0f, wy = yf - y0f;
            float omwx = 1.0f - wx, omwy = 1.0f - wy;

            int i00 = y0 * W_ + x0;
            int i01 = y0 * W_ + x1;
            int i10 = y1 * W_ + x0;
            int i11 = y1 * W_ + x1;

            const float* tb = t   + (size_t)sb * C_ * HW_;
            float*       ob = out + (size_t)sb * C_ * HW_ + y * W_ + x;
            #pragma unroll 4
            for (int c = 0; c < C_; ++c) {
                const float* tc = tb + (size_t)c * HW_;
                float top = tc[i00] * omwx + tc[i01] * wx;
                float bot = tc[i10] * omwx + tc[i11] * wx;
                float v = top * omwy + bot * wy;
                __builtin_nontemporal_store(v, ob + (size_t)c * HW_);
            }
        }
        __syncthreads();
    }
}

// ---------------------------------------------------------------------------
extern "C" void kernel_launch(void* const* d_in, const int* in_sizes, int n_in,
                              void* d_out, int out_size, void* d_ws, size_t ws_size,
                              hipStream_t stream) {
    const float* t       = (const float*)d_in[0];
    const float* rgb     = (const float*)d_in[1];
    const float* fc_w    = (const float*)d_in[2];
    const float* fc_b    = (const float*)d_in[3];
    const float* init_cp = (const float*)d_in[4];

    float* out    = (float*)d_out;
    float* cp_out = out + (size_t)B_ * C_ * HW_;

    int*    flags     = (int*)d_ws;                       // 64 ints
    float*  feat_part = (float*)((char*)d_ws + 1024);     // 8*128*2 f32 = 8 KB
    double* Wm        = (double*)((char*)d_ws + 16384);   // 8*28*2 f64

    hipMemsetAsync(d_ws, 0, 256, stream);                 // reset ticket + flags
    fused_kernel<<<2048, 256, 0, stream>>>(t, rgb, fc_w, fc_b, init_cp,
                                           out, cp_out, flags, feat_part, Wm);
}

// Round 4
// 162.579 us; speedup vs baseline: 3.3016x; 3.3016x over previous
//
#include <hip/hip_runtime.h>
#include <hip/hip_bf16.h>

#define B_  8
#define C_  64
#define H_  256
#define W_  256
#define HW_ (H_ * W_)
#define NP_ 25          // NUM_POINTS
#define NA_ 28          // N + 3 (augmented TPS system size)
#define NRHS_ 16        // 8 batches x 2 coords
#define NCOL_ (NA_ + NRHS_)   // 44
#define PARTS_ 8              // chunks per channel
#define CHUNK_ (HW_ / PARTS_) // 8192 floats per chunk

typedef float f32x4 __attribute__((ext_vector_type(4)));

// ---------------------------------------------------------------------------
// Kernel 1: partial sums for per-(b,c) mean of concat([t, rgb]).
// 4096 blocks; each block reads one 32KB chunk of a t-channel AND the matching
// chunk of the rgb-channel (two concurrent streams, 16 float4 in flight per
// thread). rgb uses nontemporal loads (never reused -> stream from HBM, keep
// L3 for t). t uses normal loads (L3-resident for the sample kernel).
// ---------------------------------------------------------------------------
__global__ __launch_bounds__(256) void mean_partial_kernel(const float* __restrict__ t,
                                                           const float* __restrict__ rgb,
                                                           float* __restrict__ partial) {
    int blk  = blockIdx.x;        // 0..4095
    int part = blk & 7;
    int idx  = blk >> 3;          // 0..511
    int b    = idx >> 6;
    int c    = idx & 63;

    size_t off = ((size_t)(b * C_ + c)) * HW_ + (size_t)part * CHUNK_;
    const f32x4* t4 = (const f32x4*)(t + off);
    const f32x4* r4 = (const f32x4*)(rgb + off);

    float at = 0.f, ar = 0.f;
    int base = threadIdx.x;
    #pragma unroll
    for (int k = 0; k < CHUNK_ / 4 / 256; ++k) {     // 8 iters, 2 streams
        f32x4 v = t4[base + k * 256];
        f32x4 w = __builtin_nontemporal_load(r4 + base + k * 256);
        at += (v.x + v.y) + (v.z + v.w);
        ar += (w.x + w.y) + (w.z + w.w);
    }
    #pragma unroll
    for (int o = 32; o > 0; o >>= 1) {
        at += __shfl_down(at, o);
        ar += __shfl_down(ar, o);
    }
    __shared__ float redt[4], redr[4];
    if ((threadIdx.x & 63) == 0) {
        redt[threadIdx.x >> 6] = at;
        redr[threadIdx.x >> 6] = ar;
    }
    __syncthreads();
    if (threadIdx.x == 0) {
        // feat layout: [b][0:64]=mean(t), [b][64:128]=mean(rgb)
        partial[(b * 128 + c) * PARTS_ + part]      = (redt[0] + redt[1]) + (redt[2] + redt[3]);
        partial[(b * 128 + 64 + c) * PARTS_ + part] = (redr[0] + redr[1]) + (redr[2] + redr[3]);
    }
}

// ---------------------------------------------------------------------------
// Kernel 2: reduce partials -> feat; delta = feat @ fc_w^T + fc_b;
// cp = init_cp + delta (second output); build TPS L (28x28, f64) and
// Gauss-Jordan solve for all 8 batches x 2 coords -> Wm[8][28][2] f64 in ws.
// ---------------------------------------------------------------------------
__global__ __launch_bounds__(256) void solve_kernel(const float* __restrict__ partial,
                                                    const float* __restrict__ fc_w,
                                                    const float* __restrict__ fc_b,
                                                    const float* __restrict__ init_cp,
                                                    float* __restrict__ cp_out,
                                                    double* __restrict__ Wm) {
    __shared__ float  s_feat[B_ * 128];
    __shared__ float  s_cp[B_][2 * NP_];
    __shared__ double P[NP_][2];
    __shared__ double A[NA_][NCOL_];
    __shared__ double f[NA_];
    __shared__ int    s_piv;
    __shared__ double s_pv;
    int tid = threadIdx.x;

    // Phase 0: deterministic fixed-order reduction of partials -> feat
    for (int i = tid; i < B_ * 128; i += 256) {
        const float* p = partial + i * PARTS_;
        float s = 0.f;
        #pragma unroll
        for (int j = 0; j < PARTS_; ++j) s += p[j];
        s_feat[i] = s * (1.0f / (float)HW_);
    }
    if (tid < 2 * NP_) ((double*)P)[tid] = (double)init_cp[tid];
    __syncthreads();

    // Phase A: cp = init_cp + (feat @ fc_w^T + fc_b)
    for (int i = tid; i < B_ * 2 * NP_; i += 256) {
        int b = i / (2 * NP_), j = i % (2 * NP_);
        float acc = fc_b[j];
        const float* w  = fc_w + j * 128;
        const float* fe = s_feat + b * 128;
        #pragma unroll 8
        for (int c = 0; c < 128; ++c) acc += fe[c] * w[c];
        float cpv = init_cp[j] + acc;
        s_cp[b][j] = cpv;
        cp_out[b * 2 * NP_ + j] = cpv;   // second tuple output (f32)
    }
    __syncthreads();

    // Phase B: build augmented [L | Y]
    for (int i = tid; i < NA_ * NCOL_; i += 256) {
        int r = i / NCOL_, cc = i % NCOL_;
        double v;
        if (cc < NA_) {
            if (r < NP_ && cc < NP_) {
                double dx = P[r][0] - P[cc][0];
                double dy = P[r][1] - P[cc][1];
                double d2 = dx * dx + dy * dy;
                v = d2 * log(d2 + 1e-6);
            } else if (r < NP_) {
                v = (cc == NP_) ? 1.0 : ((cc == NP_ + 1) ? P[r][0] : P[r][1]);
            } else if (cc < NP_) {
                v = (r == NP_) ? 1.0 : ((r == NP_ + 1) ? P[cc][0] : P[cc][1]);
            } else {
                v = 0.0;
            }
        } else {
            int y = cc - NA_;           // b*2 + k
            int b = y >> 1, k = y & 1;
            v = (r < NP_) ? (double)s_cp[b][r * 2 + k] : 0.0;
        }
        A[r][cc] = v;
    }
    __syncthreads();

    // Phase C: Gauss-Jordan with partial pivoting (f64)
    for (int k = 0; k < NA_; ++k) {
        if (tid == 0) {
            int piv = k; double best = fabs(A[k][k]);
            for (int r = k + 1; r < NA_; ++r) {
                double v = fabs(A[r][k]);
                if (v > best) { best = v; piv = r; }
            }
            s_piv = piv;
        }
        __syncthreads();
        int piv = s_piv;
        if (piv != k) {
            for (int j = tid; j < NCOL_; j += 256) {
                double tmp = A[k][j]; A[k][j] = A[piv][j]; A[piv][j] = tmp;
            }
        }
        __syncthreads();
        if (tid == 0) s_pv = 1.0 / A[k][k];
        __syncthreads();
        double pv = s_pv;
        for (int j = tid; j < NCOL_; j += 256) A[k][j] *= pv;
        __syncthreads();
        if (tid < NA_) f[tid] = A[tid][k];
        __syncthreads();
        for (int i = tid; i < NA_ * NCOL_; i += 256) {
            int r = i / NCOL_, j = i % NCOL_;
            if (r != k) A[r][j] -= f[r] * A[k][j];
        }
        __syncthreads();
    }

    // Phase D: write Wm[b][n][c]
    for (int i = tid; i < B_ * NA_ * 2; i += 256) {
        int b = i / (NA_ * 2), rest = i % (NA_ * 2);
        int n = rest >> 1, c = rest & 1;
        Wm[i] = A[n][NA_ + b * 2 + c];
    }
}

// ---------------------------------------------------------------------------
// Kernel 3: fused TPS grid evaluation (f32 basis) + bilinear grid_sample
// (border clamp, align_corners=True) over all 64 channels. Nontemporal
// stores for out (never re-read) keep t L3-resident.
// ---------------------------------------------------------------------------
__global__ __launch_bounds__(256) void sample_kernel(const float* __restrict__ t,
                                                     const float* __restrict__ init_cp,
                                                     const double* __restrict__ Wm,
                                                     float* __restrict__ out) {
    int blk = blockIdx.x;   // b*H + y
    int b = blk >> 8;
    int y = blk & 255;
    int x = threadIdx.x;

    __shared__ float sW[NA_][2];
    __shared__ float sP[NP_][2];
    if (x < 2 * NA_)
        ((float*)sW)[x] = (float)Wm[(size_t)b * 2 * NA_ + x];
    else if (x < 2 * NA_ + 2 * NP_)
        ((float*)sP)[x - 2 * NA_] = init_cp[x - 2 * NA_];
    __syncthreads();

    float px = -1.0f + (2.0f / (float)(W_ - 1)) * (float)x;
    float py = -1.0f + (2.0f / (float)(H_ - 1)) * (float)y;

    float ax = sW[NP_][0] + px * sW[NP_ + 1][0] + py * sW[NP_ + 2][0];
    float ay = sW[NP_][1] + px * sW[NP_ + 1][1] + py * sW[NP_ + 2][1];
    #pragma unroll
    for (int n = 0; n < NP_; ++n) {
        float dx = px - sP[n][0];
        float dy = py - sP[n][1];
        float d2 = dx * dx + dy * dy;
        float u  = d2 * logf(d2 + 1e-6f);
        ax += u * sW[n][0];
        ay += u * sW[n][1];
    }

    float xf = fminf(fmaxf((ax + 1.0f) * 0.5f * (float)(W_ - 1), 0.0f), (float)(W_ - 1));
    float yf = fminf(fmaxf((ay + 1.0f) * 0.5f * (float)(H_ - 1), 0.0f), (float)(H_ - 1));
    float x0f = floorf(xf), y0f = floorf(yf);
    int x0 = (int)x0f, y0 = (int)y0f;
    int x1 = min(x0 + 1, W_ - 1);
    int y1 = min(y0 + 1, H_ - 1);
    float wx = xf - x0f, wy = yf - y0f;
    float omwx = 1.0f - wx, omwy = 1.0f - wy;

    int i00 = y0 * W_ + x0;
    int i01 = y0 * W_ + x1;
    int i10 = y1 * W_ + x0;
    int i11 = y1 * W_ + x1;

    const float* tb = t   + (size_t)b * C_ * HW_;
    float*       ob = out + (size_t)b * C_ * HW_ + y * W_ + x;
    #pragma unroll 4
    for (int c = 0; c < C_; ++c) {
        const float* tc = tb + (size_t)c * HW_;
        float top = tc[i00] * omwx + tc[i01] * wx;
        float bot = tc[i10] * omwx + tc[i11] * wx;
        float v = top * omwy + bot * wy;
        __builtin_nontemporal_store(v, ob + (size_t)c * HW_);
    }
}

// ---------------------------------------------------------------------------
extern "C" void kernel_launch(void* const* d_in, const int* in_sizes, int n_in,
                              void* d_out, int out_size, void* d_ws, size_t ws_size,
                              hipStream_t stream) {
    const float* t       = (const float*)d_in[0];
    const float* rgb     = (const float*)d_in[1];
    const float* fc_w    = (const float*)d_in[2];
    const float* fc_b    = (const float*)d_in[3];
    const float* init_cp = (const float*)d_in[4];

    float* out    = (float*)d_out;
    float* cp_out = out + (size_t)B_ * C_ * HW_;   // tuple output #2

    float*  partial = (float*)d_ws;                    // 1024*8 f32 = 32 KB
    double* Wm      = (double*)((char*)d_ws + 32768);  // 8*28*2 f64

    mean_partial_kernel<<<B_ * C_ * PARTS_, 256, 0, stream>>>(t, rgb, partial);
    solve_kernel<<<1, 256, 0, stream>>>(partial, fc_w, fc_b, init_cp, cp_out, Wm);
    sample_kernel<<<B_ * H_, 256, 0, stream>>>(t, init_cp, Wm, out);
}

// Round 5
// 161.442 us; speedup vs baseline: 3.3249x; 1.0070x over previous
//
#include <hip/hip_runtime.h>
#include <hip/hip_bf16.h>

#define B_  8
#define C_  64
#define H_  256
#define W_  256
#define HW_ (H_ * W_)
#define NP_ 25          // NUM_POINTS
#define NA_ 28          // N + 3 (augmented TPS system size)
#define NRHS_ 16        // 8 batches x 2 coords
#define NCOL_ (NA_ + NRHS_)   // 44
#define PARTS_ 8              // chunks per channel
#define CHUNK_ (HW_ / PARTS_) // 8192 floats per chunk

typedef float f32x4 __attribute__((ext_vector_type(4)));

// ---------------------------------------------------------------------------
// Kernel 1: partial sums for per-(b,c) mean of concat([t, rgb]).
// 4096 blocks; each block reads one 32KB chunk of a t-channel AND the matching
// chunk of the rgb-channel. All 16 float4 loads are issued into register
// arrays BEFORE any accumulation -> 16 outstanding loads/thread (Little's law:
// was latency-bound at ~4 in flight = 1.8 TB/s/stream). rgb uses nontemporal
// loads (never reused); t stays L3-resident for the sample kernel.
// ---------------------------------------------------------------------------
__global__ __launch_bounds__(256) void mean_partial_kernel(const float* __restrict__ t,
                                                           const float* __restrict__ rgb,
                                                           float* __restrict__ partial) {
    int blk  = blockIdx.x;        // 0..4095
    int part = blk & 7;
    int idx  = blk >> 3;          // 0..511
    int b    = idx >> 6;
    int c    = idx & 63;

    size_t off = ((size_t)(b * C_ + c)) * HW_ + (size_t)part * CHUNK_;
    const f32x4* t4 = (const f32x4*)(t + off);
    const f32x4* r4 = (const f32x4*)(rgb + off);
    int base = threadIdx.x;

    f32x4 vt[8], vr[8];
    #pragma unroll
    for (int k = 0; k < 8; ++k) vt[k] = t4[base + k * 256];
    #pragma unroll
    for (int k = 0; k < 8; ++k) vr[k] = __builtin_nontemporal_load(r4 + base + k * 256);

    float at = 0.f, ar = 0.f;
    #pragma unroll
    for (int k = 0; k < 8; ++k) {
        at += (vt[k].x + vt[k].y) + (vt[k].z + vt[k].w);
        ar += (vr[k].x + vr[k].y) + (vr[k].z + vr[k].w);
    }
    #pragma unroll
    for (int o = 32; o > 0; o >>= 1) {
        at += __shfl_down(at, o);
        ar += __shfl_down(ar, o);
    }
    __shared__ float redt[4], redr[4];
    if ((threadIdx.x & 63) == 0) {
        redt[threadIdx.x >> 6] = at;
        redr[threadIdx.x >> 6] = ar;
    }
    __syncthreads();
    if (threadIdx.x == 0) {
        // feat layout: [b][0:64]=mean(t), [b][64:128]=mean(rgb)
        partial[(b * 128 + c) * PARTS_ + part]      = (redt[0] + redt[1]) + (redt[2] + redt[3]);
        partial[(b * 128 + 64 + c) * PARTS_ + part] = (redr[0] + redr[1]) + (redr[2] + redr[3]);
    }
}

// ---------------------------------------------------------------------------
// Kernel 2: reduce partials -> feat; delta = feat @ fc_w^T + fc_b;
// cp = init_cp + delta (second output); build TPS L (28x28, f64) and
// Gauss-Jordan solve for all 8 batches x 2 coords -> Wm[8][28][2] f64 in ws.
// ---------------------------------------------------------------------------
__global__ __launch_bounds__(256) void solve_kernel(const float* __restrict__ partial,
                                                    const float* __restrict__ fc_w,
                                                    const float* __restrict__ fc_b,
                                                    const float* __restrict__ init_cp,
                                                    float* __restrict__ cp_out,
                                                    double* __restrict__ Wm) {
    __shared__ float  s_feat[B_ * 128];
    __shared__ float  s_cp[B_][2 * NP_];
    __shared__ double P[NP_][2];
    __shared__ double A[NA_][NCOL_];
    __shared__ double f[NA_];
    __shared__ int    s_piv;
    __shared__ double s_pv;
    int tid = threadIdx.x;

    for (int i = tid; i < B_ * 128; i += 256) {
        const float* p = partial + i * PARTS_;
        float s = 0.f;
        #pragma unroll
        for (int j = 0; j < PARTS_; ++j) s += p[j];
        s_feat[i] = s * (1.0f / (float)HW_);
    }
    if (tid < 2 * NP_) ((double*)P)[tid] = (double)init_cp[tid];
    __syncthreads();

    for (int i = tid; i < B_ * 2 * NP_; i += 256) {
        int b = i / (2 * NP_), j = i % (2 * NP_);
        float acc = fc_b[j];
        const float* w  = fc_w + j * 128;
        const float* fe = s_feat + b * 128;
        #pragma unroll 8
        for (int c = 0; c < 128; ++c) acc += fe[c] * w[c];
        float cpv = init_cp[j] + acc;
        s_cp[b][j] = cpv;
        cp_out[b * 2 * NP_ + j] = cpv;   // second tuple output (f32)
    }
    __syncthreads();

    for (int i = tid; i < NA_ * NCOL_; i += 256) {
        int r = i / NCOL_, cc = i % NCOL_;
        double v;
        if (cc < NA_) {
            if (r < NP_ && cc < NP_) {
                double dx = P[r][0] - P[cc][0];
                double dy = P[r][1] - P[cc][1];
                double d2 = dx * dx + dy * dy;
                v = d2 * log(d2 + 1e-6);
            } else if (r < NP_) {
                v = (cc == NP_) ? 1.0 : ((cc == NP_ + 1) ? P[r][0] : P[r][1]);
            } else if (cc < NP_) {
                v = (r == NP_) ? 1.0 : ((r == NP_ + 1) ? P[cc][0] : P[cc][1]);
            } else {
                v = 0.0;
            }
        } else {
            int y = cc - NA_;
            int b = y >> 1, k = y & 1;
            v = (r < NP_) ? (double)s_cp[b][r * 2 + k] : 0.0;
        }
        A[r][cc] = v;
    }
    __syncthreads();

    for (int k = 0; k < NA_; ++k) {
        if (tid == 0) {
            int piv = k; double best = fabs(A[k][k]);
            for (int r = k + 1; r < NA_; ++r) {
                double v = fabs(A[r][k]);
                if (v > best) { best = v; piv = r; }
            }
            s_piv = piv;
        }
        __syncthreads();
        int piv = s_piv;
        if (piv != k) {
            for (int j = tid; j < NCOL_; j += 256) {
                double tmp = A[k][j]; A[k][j] = A[piv][j]; A[piv][j] = tmp;
            }
        }
        __syncthreads();
        if (tid == 0) s_pv = 1.0 / A[k][k];
        __syncthreads();
        double pv = s_pv;
        for (int j = tid; j < NCOL_; j += 256) A[k][j] *= pv;
        __syncthreads();
        if (tid < NA_) f[tid] = A[tid][k];
        __syncthreads();
        for (int i = tid; i < NA_ * NCOL_; i += 256) {
            int r = i / NCOL_, j = i % NCOL_;
            if (r != k) A[r][j] -= f[r] * A[k][j];
        }
        __syncthreads();
    }

    for (int i = tid; i < B_ * NA_ * 2; i += 256) {
        int b = i / (NA_ * 2), rest = i % (NA_ * 2);
        int n = rest >> 1, c = rest & 1;
        Wm[i] = A[n][NA_ + b * 2 + c];
    }
}

// ---------------------------------------------------------------------------
// Kernel 3: fused TPS grid evaluation (f32 basis) + bilinear grid_sample
// (border clamp, align_corners=True). 8-channel batches: all 32 tap loads
// issued into register arrays before any FMA (deep in-flight), nontemporal
// stores for out (never re-read) keep t L3-resident.
// ---------------------------------------------------------------------------
__global__ __launch_bounds__(256) void sample_kernel(const float* __restrict__ t,
                                                     const float* __restrict__ init_cp,
                                                     const double* __restrict__ Wm,
                                                     float* __restrict__ out) {
    int blk = blockIdx.x;   // b*H + y
    int b = blk >> 8;
    int y = blk & 255;
    int x = threadIdx.x;

    __shared__ float sW[NA_][2];
    __shared__ float sP[NP_][2];
    if (x < 2 * NA_)
        ((float*)sW)[x] = (float)Wm[(size_t)b * 2 * NA_ + x];
    else if (x < 2 * NA_ + 2 * NP_)
        ((float*)sP)[x - 2 * NA_] = init_cp[x - 2 * NA_];
    __syncthreads();

    float px = -1.0f + (2.0f / (float)(W_ - 1)) * (float)x;
    float py = -1.0f + (2.0f / (float)(H_ - 1)) * (float)y;

    float ax = sW[NP_][0] + px * sW[NP_ + 1][0] + py * sW[NP_ + 2][0];
    float ay = sW[NP_][1] + px * sW[NP_ + 1][1] + py * sW[NP_ + 2][1];
    #pragma unroll
    for (int n = 0; n < NP_; ++n) {
        float dx = px - sP[n][0];
        float dy = py - sP[n][1];
        float d2 = dx * dx + dy * dy;
        float u  = d2 * logf(d2 + 1e-6f);
        ax += u * sW[n][0];
        ay += u * sW[n][1];
    }

    float xf = fminf(fmaxf((ax + 1.0f) * 0.5f * (float)(W_ - 1), 0.0f), (float)(W_ - 1));
    float yf = fminf(fmaxf((ay + 1.0f) * 0.5f * (float)(H_ - 1), 0.0f), (float)(H_ - 1));
    float x0f = floorf(xf), y0f = floorf(yf);
    int x0 = (int)x0f, y0 = (int)y0f;
    int x1 = min(x0 + 1, W_ - 1);
    int y1 = min(y0 + 1, H_ - 1);
    float wx = xf - x0f, wy = yf - y0f;
    float omwx = 1.0f - wx, omwy = 1.0f - wy;

    int i00 = y0 * W_ + x0;
    int i01 = y0 * W_ + x1;
    int i10 = y1 * W_ + x0;
    int i11 = y1 * W_ + x1;

    const float* tb = t   + (size_t)b * C_ * HW_;
    float*       ob = out + (size_t)b * C_ * HW_ + y * W_ + x;

    #pragma unroll 2
    for (int cc = 0; cc < C_; cc += 8) {
        float a00[8], a01[8], a10[8], a11[8];
        #pragma unroll
        for (int j = 0; j < 8; ++j) {
            const float* tc = tb + (size_t)(cc + j) * HW_;
            a00[j] = tc[i00];
            a01[j] = tc[i01];
            a10[j] = tc[i10];
            a11[j] = tc[i11];
        }
        #pragma unroll
        for (int j = 0; j < 8; ++j) {
            float top = a00[j] * omwx + a01[j] * wx;
            float bot = a10[j] * omwx + a11[j] * wx;
            __builtin_nontemporal_store(top * omwy + bot * wy, ob + (size_t)(cc + j) * HW_);
        }
    }
}

// ---------------------------------------------------------------------------
extern "C" void kernel_launch(void* const* d_in, const int* in_sizes, int n_in,
                              void* d_out, int out_size, void* d_ws, size_t ws_size,
                              hipStream_t stream) {
    const float* t       = (const float*)d_in[0];
    const float* rgb     = (const float*)d_in[1];
    const float* fc_w    = (const float*)d_in[2];
    const float* fc_b    = (const float*)d_in[3];
    const float* init_cp = (const float*)d_in[4];

    float* out    = (float*)d_out;
    float* cp_out = out + (size_t)B_ * C_ * HW_;   // tuple output #2

    float*  partial = (float*)d_ws;                    // 1024*8 f32 = 32 KB
    double* Wm      = (double*)((char*)d_ws + 32768);  // 8*28*2 f64

    mean_partial_kernel<<<B_ * C_ * PARTS_, 256, 0, stream>>>(t, rgb, partial);
    solve_kernel<<<1, 256, 0, stream>>>(partial, fc_w, fc_b, init_cp, cp_out, Wm);
    sample_kernel<<<B_ * H_, 256, 0, stream>>>(t, init_cp, Wm, out);
}

// Round 6
// 139.185 us; speedup vs baseline: 3.8566x; 1.1599x over previous
//
#include <hip/hip_runtime.h>
#include <hip/hip_bf16.h>

#define B_  8
#define C_  64
#define H_  256
#define W_  256
#define HW_ (H_ * W_)
#define NP_ 25          // NUM_POINTS
#define NA_ 28          // N + 3 (augmented TPS system size)
#define NRHS_ 16        // 8 batches x 2 coords
#define NCOL_ (NA_ + NRHS_)   // 44
#define PARTS_ 4              // chunks per channel
#define CHUNK_ (HW_ / PARTS_) // 16384 floats per chunk

typedef float f32x4 __attribute__((ext_vector_type(4)));

// ---------------------------------------------------------------------------
// Kernel 1: partial sums for per-(b,c) mean of concat([t, rgb]).
// 2048 blocks -> fully resident (8 blocks/CU), no sequential block drain.
// XCD-contiguous partition: bid&7 = XCD index (HW round-robin), so XCD x
// owns batch b=x (contiguous 16.8 MB of t and of rgb) -> private address
// range per XCD L2, DRAM page locality, and t[b=x] left warm for the sample
// kernel on the same XCD. 32 loads/thread issued in 2 batches of 16.
// rgb nontemporal (never reused); t normal (L3-resident for sampling).
// ---------------------------------------------------------------------------
__global__ __launch_bounds__(256) void mean_partial_kernel(const float* __restrict__ t,
                                                           const float* __restrict__ rgb,
                                                           float* __restrict__ partial) {
    int bid   = blockIdx.x;            // 0..2047
    int xcd   = bid & 7;
    int li    = bid >> 3;              // 0..255 within XCD
    int plane = xcd * 64 + (li >> 2);  // = b*64 + c  (b == xcd)
    int part  = li & 3;
    int b = plane >> 6, c = plane & 63;

    size_t off = (size_t)plane * HW_ + (size_t)part * CHUNK_;
    const f32x4* t4 = (const f32x4*)(t + off);
    const f32x4* r4 = (const f32x4*)(rgb + off);
    int base = threadIdx.x;

    float at = 0.f, ar = 0.f;
    #pragma unroll
    for (int half = 0; half < 2; ++half) {
        f32x4 va[8], vb[8];
        #pragma unroll
        for (int k = 0; k < 8; ++k) va[k] = t4[base + (half * 8 + k) * 256];
        #pragma unroll
        for (int k = 0; k < 8; ++k) vb[k] = __builtin_nontemporal_load(r4 + base + (half * 8 + k) * 256);
        #pragma unroll
        for (int k = 0; k < 8; ++k) {
            at += (va[k].x + va[k].y) + (va[k].z + va[k].w);
            ar += (vb[k].x + vb[k].y) + (vb[k].z + vb[k].w);
        }
    }
    #pragma unroll
    for (int o = 32; o > 0; o >>= 1) {
        at += __shfl_down(at, o);
        ar += __shfl_down(ar, o);
    }
    __shared__ float redt[4], redr[4];
    if ((threadIdx.x & 63) == 0) {
        redt[threadIdx.x >> 6] = at;
        redr[threadIdx.x >> 6] = ar;
    }
    __syncthreads();
    if (threadIdx.x == 0) {
        // feat layout: [b][0:64]=mean(t), [b][64:128]=mean(rgb)
        partial[(b * 128 + c) * PARTS_ + part]      = (redt[0] + redt[1]) + (redt[2] + redt[3]);
        partial[(b * 128 + 64 + c) * PARTS_ + part] = (redr[0] + redr[1]) + (redr[2] + redr[3]);
    }
}

// ---------------------------------------------------------------------------
// Kernel 2: reduce partials -> feat; delta = feat @ fc_w^T + fc_b;
// cp = init_cp + delta (second output); build TPS L (28x28, f64) and
// Gauss-Jordan solve for all 8 batches x 2 coords -> Wm[8][28][2] f64 in ws.
// ---------------------------------------------------------------------------
__global__ __launch_bounds__(256) void solve_kernel(const float* __restrict__ partial,
                                                    const float* __restrict__ fc_w,
                                                    const float* __restrict__ fc_b,
                                                    const float* __restrict__ init_cp,
                                                    float* __restrict__ cp_out,
                                                    double* __restrict__ Wm) {
    __shared__ float  s_feat[B_ * 128];
    __shared__ float  s_cp[B_][2 * NP_];
    __shared__ double P[NP_][2];
    __shared__ double A[NA_][NCOL_];
    __shared__ double f[NA_];
    __shared__ int    s_piv;
    __shared__ double s_pv;
    int tid = threadIdx.x;

    for (int i = tid; i < B_ * 128; i += 256) {
        const float* p = partial + i * PARTS_;
        float s = 0.f;
        #pragma unroll
        for (int j = 0; j < PARTS_; ++j) s += p[j];
        s_feat[i] = s * (1.0f / (float)HW_);
    }
    if (tid < 2 * NP_) ((double*)P)[tid] = (double)init_cp[tid];
    __syncthreads();

    for (int i = tid; i < B_ * 2 * NP_; i += 256) {
        int b = i / (2 * NP_), j = i % (2 * NP_);
        float acc = fc_b[j];
        const float* w  = fc_w + j * 128;
        const float* fe = s_feat + b * 128;
        #pragma unroll 8
        for (int c = 0; c < 128; ++c) acc += fe[c] * w[c];
        float cpv = init_cp[j] + acc;
        s_cp[b][j] = cpv;
        cp_out[b * 2 * NP_ + j] = cpv;   // second tuple output (f32)
    }
    __syncthreads();

    for (int i = tid; i < NA_ * NCOL_; i += 256) {
        int r = i / NCOL_, cc = i % NCOL_;
        double v;
        if (cc < NA_) {
            if (r < NP_ && cc < NP_) {
                double dx = P[r][0] - P[cc][0];
                double dy = P[r][1] - P[cc][1];
                double d2 = dx * dx + dy * dy;
                v = d2 * log(d2 + 1e-6);
            } else if (r < NP_) {
                v = (cc == NP_) ? 1.0 : ((cc == NP_ + 1) ? P[r][0] : P[r][1]);
            } else if (cc < NP_) {
                v = (r == NP_) ? 1.0 : ((r == NP_ + 1) ? P[cc][0] : P[cc][1]);
            } else {
                v = 0.0;
            }
        } else {
            int y = cc - NA_;
            int b = y >> 1, k = y & 1;
            v = (r < NP_) ? (double)s_cp[b][r * 2 + k] : 0.0;
        }
        A[r][cc] = v;
    }
    __syncthreads();

    for (int k = 0; k < NA_; ++k) {
        if (tid == 0) {
            int piv = k; double best = fabs(A[k][k]);
            for (int r = k + 1; r < NA_; ++r) {
                double v = fabs(A[r][k]);
                if (v > best) { best = v; piv = r; }
            }
            s_piv = piv;
        }
        __syncthreads();
        int piv = s_piv;
        if (piv != k) {
            for (int j = tid; j < NCOL_; j += 256) {
                double tmp = A[k][j]; A[k][j] = A[piv][j]; A[piv][j] = tmp;
            }
        }
        __syncthreads();
        if (tid == 0) s_pv = 1.0 / A[k][k];
        __syncthreads();
        double pv = s_pv;
        for (int j = tid; j < NCOL_; j += 256) A[k][j] *= pv;
        __syncthreads();
        if (tid < NA_) f[tid] = A[tid][k];
        __syncthreads();
        for (int i = tid; i < NA_ * NCOL_; i += 256) {
            int r = i / NCOL_, j = i % NCOL_;
            if (r != k) A[r][j] -= f[r] * A[k][j];
        }
        __syncthreads();
    }

    for (int i = tid; i < B_ * NA_ * 2; i += 256) {
        int b = i / (NA_ * 2), rest = i % (NA_ * 2);
        int n = rest >> 1, c = rest & 1;
        Wm[i] = A[n][NA_ + b * 2 + c];
    }
}

// ---------------------------------------------------------------------------
// Kernel 3: fused TPS grid eval (f32 basis) + bilinear grid_sample.
// XCD-contiguous mapping: b = bid&7 (-> XCD b), y = bid>>3, so XCD x
// processes batch x with monotonically increasing y: each input row of t
// (64 KB across channels) is fetched into that XCD's L2 once and reused by
// the two adjacent output rows, halving L3->L2 fabric traffic. 8-channel
// tap batches (32 loads in flight); nontemporal stores for out.
// ---------------------------------------------------------------------------
__global__ __launch_bounds__(256) void sample_kernel(const float* __restrict__ t,
                                                     const float* __restrict__ init_cp,
                                                     const double* __restrict__ Wm,
                                                     float* __restrict__ out) {
    int b = blockIdx.x & 7;     // XCD-contiguous: batch == XCD
    int y = blockIdx.x >> 3;
    int x = threadIdx.x;

    __shared__ float sW[NA_][2];
    __shared__ float sP[NP_][2];
    if (x < 2 * NA_)
        ((float*)sW)[x] = (float)Wm[(size_t)b * 2 * NA_ + x];
    else if (x < 2 * NA_ + 2 * NP_)
        ((float*)sP)[x - 2 * NA_] = init_cp[x - 2 * NA_];
    __syncthreads();

    float px = -1.0f + (2.0f / (float)(W_ - 1)) * (float)x;
    float py = -1.0f + (2.0f / (float)(H_ - 1)) * (float)y;

    float ax = sW[NP_][0] + px * sW[NP_ + 1][0] + py * sW[NP_ + 2][0];
    float ay = sW[NP_][1] + px * sW[NP_ + 1][1] + py * sW[NP_ + 2][1];
    #pragma unroll
    for (int n = 0; n < NP_; ++n) {
        float dx = px - sP[n][0];
        float dy = py - sP[n][1];
        float d2 = dx * dx + dy * dy;
        float u  = d2 * logf(d2 + 1e-6f);
        ax += u * sW[n][0];
        ay += u * sW[n][1];
    }

    float xf = fminf(fmaxf((ax + 1.0f) * 0.5f * (float)(W_ - 1), 0.0f), (float)(W_ - 1));
    float yf = fminf(fmaxf((ay + 1.0f) * 0.5f * (float)(H_ - 1), 0.0f), (float)(H_ - 1));
    float x0f = floorf(xf), y0f = floorf(yf);
    int x0 = (int)x0f, y0 = (int)y0f;
    int x1 = min(x0 + 1, W_ - 1);
    int y1 = min(y0 + 1, H_ - 1);
    float wx = xf - x0f, wy = yf - y0f;
    float omwx = 1.0f - wx, omwy = 1.0f - wy;

    int i00 = y0 * W_ + x0;
    int i01 = y0 * W_ + x1;
    int i10 = y1 * W_ + x0;
    int i11 = y1 * W_ + x1;

    const float* tb = t   + (size_t)b * C_ * HW_;
    float*       ob = out + (size_t)b * C_ * HW_ + y * W_ + x;

    #pragma unroll 2
    for (int cc = 0; cc < C_; cc += 8) {
        float a00[8], a01[8], a10[8], a11[8];
        #pragma unroll
        for (int j = 0; j < 8; ++j) {
            const float* tc = tb + (size_t)(cc + j) * HW_;
            a00[j] = tc[i00];
            a01[j] = tc[i01];
            a10[j] = tc[i10];
            a11[j] = tc[i11];
        }
        #pragma unroll
        for (int j = 0; j < 8; ++j) {
            float top = a00[j] * omwx + a01[j] * wx;
            float bot = a10[j] * omwx + a11[j] * wx;
            __builtin_nontemporal_store(top * omwy + bot * wy, ob + (size_t)(cc + j) * HW_);
        }
    }
}

// ---------------------------------------------------------------------------
extern "C" void kernel_launch(void* const* d_in, const int* in_sizes, int n_in,
                              void* d_out, int out_size, void* d_ws, size_t ws_size,
                              hipStream_t stream) {
    const float* t       = (const float*)d_in[0];
    const float* rgb     = (const float*)d_in[1];
    const float* fc_w    = (const float*)d_in[2];
    const float* fc_b    = (const float*)d_in[3];
    const float* init_cp = (const float*)d_in[4];

    float* out    = (float*)d_out;
    float* cp_out = out + (size_t)B_ * C_ * HW_;   // tuple output #2

    float*  partial = (float*)d_ws;                    // 1024*4 f32 = 16 KB
    double* Wm      = (double*)((char*)d_ws + 32768);  // 8*28*2 f64

    mean_partial_kernel<<<2048, 256, 0, stream>>>(t, rgb, partial);
    solve_kernel<<<1, 256, 0, stream>>>(partial, fc_w, fc_b, init_cp, cp_out, Wm);
    sample_kernel<<<B_ * H_, 256, 0, stream>>>(t, init_cp, Wm, out);
}